// Round 3
// baseline (209.777 us; speedup 1.0000x reference)
//
#include <hip/hip_runtime.h>
#include <hip/hip_bf16.h>

#define KTAG 52
#define START_TAG 50
#define STOP_TAG 51
#define TMAX 512

typedef float v2f __attribute__((ext_vector_type(2)));

__device__ __forceinline__ float rdlane(float v, int l) {
    return __int_as_float(__builtin_amdgcn_readlane(__float_as_int(v), l));
}

// Packed fp32 FMA: acc.{x,y} += a.{x,y} * b.{x,y}  (one VALU issue for 2 FMAs)
__device__ __forceinline__ void pk_fma(v2f& acc, v2f a, v2f b) {
    asm("v_pk_fma_f32 %0, %1, %2, %0" : "+v"(acc) : "v"(a), "v"(b));
}

// ---- Deterministic length-rank: perm[rank] = b, rank = #{len smaller, idx tiebreak}
// 16 blocks x 64 lanes; each lane caches 16 lens; per b: 16 cmp + wave reduce.
#define LPL 16   // lens per lane (B <= 1024)
__global__ __launch_bounds__(64) void rank_kernel(
    const int* __restrict__ lens, int* __restrict__ perm, int B)
{
    const int lane = threadIdx.x;
    int myl[LPL];
    #pragma unroll
    for (int k = 0; k < LPL; ++k) {
        int j = lane * LPL + k;
        myl[k] = (j < B) ? lens[j] : 0x7fffffff;
    }
    const int base = blockIdx.x * 64;
    for (int i = 0; i < 64; ++i) {
        int b = base + i;
        if (b >= B) break;
        int Lb = lens[b];            // uniform -> scalar load
        int r = 0;
        #pragma unroll
        for (int k = 0; k < LPL; ++k) {
            int j = lane * LPL + k;
            r += (myl[k] < Lb || (myl[k] == Lb && j < b)) ? 1 : 0;
        }
        #pragma unroll
        for (int off = 32; off; off >>= 1) r += __shfl_xor(r, off);
        if (lane == 0) perm[r] = b;
    }
}

// ---- Main: wave w handles pair (perm[w] = short, perm[B-1-w] = long).
// Alternating steps; beta broadcast via single-wave LDS (no barrier);
// E rows shared; v_pk_fma_f32 matvec.
__global__ __launch_bounds__(64) void crf_pair_kernel(
    const float* __restrict__ logits,   // [B, T, K]
    const float* __restrict__ trans,    // [K, K]
    const int*   __restrict__ labels,   // [B, T]
    const int*   __restrict__ lens,     // [B]
    const int*   __restrict__ perm,     // [B]
    float* __restrict__ out, int B)
{
    constexpr float L2E = 1.4426950408889634f;
    constexpr float LN2 = 0.6931471805599453f;

    const int w    = blockIdx.x;
    const int lane = threadIdx.x;
    const bool active = lane < KTAG;

    const int iA = w, iB = B - 1 - w;
    const bool hasB = (iB != iA);
    const int bA = perm[iA];
    const int bB = hasB ? perm[iB] : bA;
    const int nA = lens[bA];
    const int nB = lens[bB];            // rank order => nA <= nB

    __shared__ __align__(16) float sA[64], sB[64];

    // E = exp(trans): lane's row, packed in f32 pairs (shared by both batches)
    v2f Epk[26];
    float stopE;
    {
        const float* trow = trans + (size_t)(active ? lane : 0) * KTAG;
        #pragma unroll
        for (int p = 0; p < 13; ++p) {
            float4 q = *reinterpret_cast<const float4*>(&trow[4 * p]);  // rows are 208B = 13x16B
            v2f lo, hi;
            lo.x = active ? exp2f(q.x * L2E) : 0.f;
            lo.y = active ? exp2f(q.y * L2E) : 0.f;
            hi.x = active ? exp2f(q.z * L2E) : 0.f;
            hi.y = active ? exp2f(q.w * L2E) : 0.f;
            Epk[2 * p] = lo; Epk[2 * p + 1] = hi;
        }
        stopE = active ? exp2f(trans[(size_t)STOP_TAG * KTAG + lane] * L2E) : 0.f;
    }

    const float* lgA = logits + (size_t)bA * TMAX * KTAG + (active ? lane : 0);
    const float* lgB = logits + (size_t)bB * TMAX * KTAG + (active ? lane : 0);

    float betaA = (lane == START_TAG) ? 1.f : 0.f;
    float betaB = betaA;
    sA[lane] = betaA;
    sB[lane] = betaB;
    float M2A = 0.f, M2B = 0.f;

    auto ldA = [&](int t) { int tc = t < TMAX ? t : (TMAX - 1); return lgA[tc * KTAG]; };
    auto ldB = [&](int t) { int tc = t < TMAX ? t : (TMAX - 1); return lgB[tc * KTAG]; };

    float a0 = ldA(0), a1 = ldA(1), a2 = ldA(2), a3 = ldA(3);
    float b0 = ldB(0), b1 = ldB(1), b2 = ldB(2), b3 = ldB(3);

    // one matvec step on shared array s, E in Epk; returns new beta (also stores)
    auto MATV = [&](float* s, float e) -> float {
        v2f ac0 = {0.f, 0.f}, ac1 = {0.f, 0.f};
        #pragma unroll
        for (int p = 0; p < 13; ++p) {
            float4 q = *reinterpret_cast<const float4*>(&s[4 * p]);
            v2f lo; lo.x = q.x; lo.y = q.y;
            v2f hi; hi.x = q.z; hi.y = q.w;
            pk_fma(ac0, Epk[2 * p], lo);
            pk_fma(ac1, Epk[2 * p + 1], hi);
        }
        return ((ac0.x + ac0.y) + (ac1.x + ac1.y)) * e;
    };

    int t = 0;
    // ---- paired phase: both batches step together (independent chains interleave)
    for (; t < nA; ++t) {
        float sclA = 1.f, sclB = 1.f;
        if (((t & 3) == 0) && t) {           // uniform branch, every 4 steps
            float mA = rdlane(betaA, 0), mB = rdlane(betaB, 0);
            M2A += log2f(mA); M2B += log2f(mB);
            sclA = 1.f / mA;  sclB = 1.f / mB;
        }
        // step A
        float eA = exp2f(a0 * L2E) * sclA;
        a0 = a1; a1 = a2; a2 = a3; a3 = ldA(t + 4);
        betaA = MATV(sA, eA);
        sA[lane] = betaA;                    // one full B-step before next A-read
        // step B
        float eB = exp2f(b0 * L2E) * sclB;
        b0 = b1; b1 = b2; b2 = b3; b3 = ldB(t + 4);
        betaB = MATV(sB, eB);
        sB[lane] = betaB;
    }
    // ---- solo tail: B only
    for (; t < nB; ++t) {
        float sclB = 1.f;
        if (((t & 3) == 0) && t) {
            float mB = rdlane(betaB, 0);
            M2B += log2f(mB);
            sclB = 1.f / mB;
        }
        float eB = exp2f(b0 * L2E) * sclB;
        b0 = b1; b1 = b2; b2 = b3; b3 = ldB(t + 4);
        betaB = MATV(sB, eB);
        sB[lane] = betaB;
    }

    // ---- finalize: partition + gold-path score for one batch
    auto FINISH = [&](float beta, float M2, int b, int len) {
        float s = beta * stopE;
        #pragma unroll
        for (int off = 32; off; off >>= 1) s += __shfl_xor(s, off);
        float partition = LN2 * (M2 + log2f(s));

        const int*   labp = labels + (size_t)b * TMAX;
        const float* lgb  = logits + (size_t)b * TMAX * KTAG;
        float em = 0.f, tr = 0.f;
        for (int tt = lane; tt < len; tt += 64) {
            int lab = labp[tt];
            em += lgb[tt * KTAG + lab];
            int prv = (tt == 0) ? START_TAG : labp[tt - 1];
            tr += trans[lab * KTAG + prv];
        }
        if (lane == 0) tr += trans[STOP_TAG * KTAG + labp[len - 1]];
        #pragma unroll
        for (int off = 32; off; off >>= 1) {
            em += __shfl_xor(em, off);
            tr += __shfl_xor(tr, off);
        }
        if (lane == 0) out[b] = partition + em - tr;
    };

    FINISH(betaA, M2A, bA, nA);
    if (hasB) FINISH(betaB, M2B, bB, nB);
}

extern "C" void kernel_launch(void* const* d_in, const int* in_sizes, int n_in,
                              void* d_out, int out_size, void* d_ws, size_t ws_size,
                              hipStream_t stream) {
    const float* logits = (const float*)d_in[0];
    const float* trans  = (const float*)d_in[1];
    const int*   labels = (const int*)d_in[2];
    const int*   lens   = (const int*)d_in[3];
    float* out = (float*)d_out;

    const int B = in_sizes[3];
    int* perm = (int*)d_ws;                 // B ints

    rank_kernel<<<dim3((B + 63) / 64), dim3(64), 0, stream>>>(lens, perm, B);
    crf_pair_kernel<<<dim3((B + 1) / 2), dim3(64), 0, stream>>>(
        logits, trans, labels, lens, perm, out, B);
}

// Round 4
// 152.210 us; speedup vs baseline: 1.3782x; 1.3782x over previous
//
#include <hip/hip_runtime.h>
#include <hip/hip_bf16.h>

#define KTAG 52
#define START_TAG 50
#define STOP_TAG 51
#define TMAX 512
#define NCU 256

__device__ __forceinline__ float rdlane(float v, int l) {
    return __int_as_float(__builtin_amdgcn_readlane(__float_as_int(v), l));
}

// acc[i] = sum_j Erow[j] * v[j]  (v broadcast from lanes via v_readlane)
__device__ __forceinline__ float matv(const float* __restrict__ Erow, float v) {
    float a0 = 0.f, a1 = 0.f, a2 = 0.f, a3 = 0.f;
    #pragma unroll
    for (int j = 0; j < 13; ++j) {
        a0 = fmaf(Erow[4*j+0], rdlane(v, 4*j+0), a0);
        a1 = fmaf(Erow[4*j+1], rdlane(v, 4*j+1), a1);
        a2 = fmaf(Erow[4*j+2], rdlane(v, 4*j+2), a2);
        a3 = fmaf(Erow[4*j+3], rdlane(v, 4*j+3), a3);
    }
    return (a0 + a1) + (a2 + a3);
}

// Scaled linear-domain chain, NO LDS inside (readlane broadcast only).
// FWD:  beta' = matv(E, beta) * e_t          (e_t = exp(logit_t[lane]))
// BWD:  beta' = matv(E^T, beta * e_t)        (gamma recurrence)
// Returns final vector entry for this lane; M2 accumulates log2 of scales.
template<bool BWD>
__device__ __forceinline__ float chain(const float* __restrict__ p0, int stride,
                                       int maxk, int nsteps, const float* __restrict__ Erow,
                                       float beta, float& M2) {
    constexpr float L2E = 1.4426950408889634f;
    M2 = 0.f;

    auto lgt = [&](int k) -> float {
        int kc = k < maxk ? k : maxk;          // clamped prefetch, always in-bounds
        return p0[(long)stride * kc];
    };
    auto STEP = [&](float lg, float scl) {
        float e = exp2f(lg * L2E) * scl;
        if (BWD) beta = matv(Erow, beta * e);
        else     beta = matv(Erow, beta) * e;
    };

    float l0 = lgt(0), l1 = lgt(1), l2 = lgt(2), l3 = lgt(3);
    int k = 0;
    while (k + 4 <= nsteps) {
        float n0 = lgt(k+4), n1 = lgt(k+5), n2 = lgt(k+6), n3 = lgt(k+7);
        float scl = 1.f;
        if (k > 0) {                            // uniform; beta[0] > 0 once started
            float m = rdlane(beta, 0);
            M2 += log2f(m);
            scl = 1.f / m;
        }
        STEP(l0, scl); STEP(l1, 1.f); STEP(l2, 1.f); STEP(l3, 1.f);
        l0 = n0; l1 = n1; l2 = n2; l3 = n3;
        k += 4;
    }
    if (k < nsteps) {
        float scl = 1.f;
        if (k > 0) {
            float m = rdlane(beta, 0);
            M2 += log2f(m);
            scl = 1.f / m;
        }
        STEP(l0, scl); ++k;
        if (k < nsteps) { STEP(l1, 1.f); ++k; }
        if (k < nsteps) { STEP(l2, 1.f); ++k; }
    }
    return beta;
}

// ---- Deterministic length-rank: perm[rank] = b (ascending len, idx tiebreak)
#define LPL 16
__global__ __launch_bounds__(64) void rank_kernel(
    const int* __restrict__ lens, int* __restrict__ perm, int B)
{
    const int lane = threadIdx.x;
    int myl[LPL];
    #pragma unroll
    for (int k = 0; k < LPL; ++k) {
        int j = lane * LPL + k;
        myl[k] = (j < B) ? lens[j] : 0x7fffffff;
    }
    const int base = blockIdx.x * 64;
    for (int i = 0; i < 64; ++i) {
        int b = base + i;
        if (b >= B) break;
        int Lb = lens[b];
        int r = 0;
        #pragma unroll
        for (int k = 0; k < LPL; ++k) {
            int j = lane * LPL + k;
            r += (myl[k] < Lb || (myl[k] == Lb && j < b)) ? 1 : 0;
        }
        #pragma unroll
        for (int off = 32; off; off >>= 1) r += __shfl_xor(r, off);
        if (lane == 0) perm[r] = b;
    }
}

// ---- Main: one block (2 waves) per batch. Wave0 = forward half, wave1 =
// backward half. Combine with a dot product after ONE barrier (outside loops).
// Block->rank interleave co-locates equal-length blocks on the same CU.
__global__ __launch_bounds__(128) void crf_split_kernel(
    const float* __restrict__ logits,   // [B, T, K]
    const float* __restrict__ trans,    // [K, K]
    const int*   __restrict__ labels,   // [B, T]
    const int*   __restrict__ lens,     // [B]
    const int*   __restrict__ perm,     // [B]
    float* __restrict__ out, int B)
{
    constexpr float L2E = 1.4426950408889634f;
    constexpr float LN2 = 0.6931471805599453f;

    const int blk  = blockIdx.x;
    const int wave = threadIdx.x >> 6;
    const int lane = threadIdx.x & 63;
    const bool active = lane < KTAG;
    const bool bwd = (wave == 1);

    // rank -> CU co-location (round-robin dispatch: blk and blk+NCU share a CU)
    int r = blk;
    if ((B % NCU) == 0) {
        int per = B / NCU;
        r = (blk % NCU) * per + (blk / NCU);
    }
    const int batch = perm[r];
    const int len = lens[batch];
    const int mid = len >> 1;               // forward steps; backward = len-mid >= 1

    // E row: wave0 = exp(trans[lane][j]), wave1 = exp(trans[j][lane])
    float Erow[KTAG];
    #pragma unroll
    for (int j = 0; j < KTAG; ++j) {
        float tv = active ? (bwd ? trans[j * KTAG + lane]
                                 : trans[(size_t)lane * KTAG + j]) : 0.f;
        Erow[j] = active ? exp2f(tv * L2E) : 0.f;
    }

    const float* base = logits + (size_t)batch * TMAX * KTAG + (active ? lane : 0);

    float M2, beta;
    if (bwd) {
        float b0 = active ? exp2f(trans[STOP_TAG * KTAG + lane] * L2E) : 0.f;
        beta = chain<true>(base + (size_t)(len - 1) * KTAG, -KTAG,
                           len - 1, len - mid, Erow, b0, M2);
    } else {
        float b0 = (lane == START_TAG) ? 1.f : 0.f;
        beta = chain<false>(base, KTAG, TMAX - 1, mid, Erow, b0, M2);
    }

    __shared__ float sB[64];
    __shared__ float sM2f;
    if (!bwd) {
        sB[lane] = beta;
        if (lane == 0) sM2f = M2;
    }
    __syncthreads();

    if (bwd) {
        // Z = gamma^T beta_mid
        float d = beta * sB[lane];
        #pragma unroll
        for (int off = 32; off; off >>= 1) d += __shfl_xor(d, off);
        float partition = LN2 * (sM2f + M2 + log2f(d));

        // gold-path scores (t-parallel across 64 lanes)
        const int*   labp = labels + (size_t)batch * TMAX;
        const float* lgb  = logits + (size_t)batch * TMAX * KTAG;
        float em = 0.f, tr = 0.f;
        for (int tt = lane; tt < len; tt += 64) {
            int lab = labp[tt];
            em += lgb[tt * KTAG + lab];
            int prv = (tt == 0) ? START_TAG : labp[tt - 1];
            tr += trans[lab * KTAG + prv];
        }
        if (lane == 0) tr += trans[STOP_TAG * KTAG + labp[len - 1]];
        #pragma unroll
        for (int off = 32; off; off >>= 1) {
            em += __shfl_xor(em, off);
            tr += __shfl_xor(tr, off);
        }
        if (lane == 0) out[batch] = partition + em - tr;
    }
}

extern "C" void kernel_launch(void* const* d_in, const int* in_sizes, int n_in,
                              void* d_out, int out_size, void* d_ws, size_t ws_size,
                              hipStream_t stream) {
    const float* logits = (const float*)d_in[0];
    const float* trans  = (const float*)d_in[1];
    const int*   labels = (const int*)d_in[2];
    const int*   lens   = (const int*)d_in[3];
    float* out = (float*)d_out;

    const int B = in_sizes[3];
    int* perm = (int*)d_ws;

    rank_kernel<<<dim3((B + 63) / 64), dim3(64), 0, stream>>>(lens, perm, B);
    crf_split_kernel<<<dim3(B), dim3(128), 0, stream>>>(
        logits, trans, labels, lens, perm, out, B);
}

// Round 7
// 127.404 us; speedup vs baseline: 1.6465x; 1.1947x over previous
//
#include <hip/hip_runtime.h>

#define KTAG 52
#define START_TAG 50
#define STOP_TAG 51
#define TMAX 512
#define NCU 256

__device__ __forceinline__ float rdlanef(float v, int l) {
    return __int_as_float(__builtin_amdgcn_readlane(__float_as_int(v), l));
}

// acc[i] = sum_j Erow[j] * v[j]  (v broadcast lane-by-lane via v_readlane)
__device__ __forceinline__ float matv(const float* __restrict__ Erow, float v) {
    float a0 = 0.f, a1 = 0.f, a2 = 0.f, a3 = 0.f;
    #pragma unroll
    for (int j = 0; j < 13; ++j) {
        a0 = fmaf(Erow[4*j+0], rdlanef(v, 4*j+0), a0);
        a1 = fmaf(Erow[4*j+1], rdlanef(v, 4*j+1), a1);
        a2 = fmaf(Erow[4*j+2], rdlanef(v, 4*j+2), a2);
        a3 = fmaf(Erow[4*j+3], rdlanef(v, 4*j+3), a3);
    }
    return (a0 + a1) + (a2 + a3);
}

// Scaled linear-domain chain, NO LDS inside (readlane broadcast only).
// FWD:  beta' = matv(E, beta) * e_t        BWD:  beta' = matv(E^T, beta * e_t)
template<bool BWD>
__device__ __forceinline__ float chain(const float* __restrict__ p0, int stride,
                                       int maxk, int nsteps, const float* __restrict__ Erow,
                                       float beta, float& M2) {
    constexpr float L2E = 1.4426950408889634f;
    M2 = 0.f;

    auto lgt = [&](int k) -> float {
        int kc = k < maxk ? k : maxk;          // clamped prefetch, always in-bounds
        return p0[(long)stride * kc];
    };
    auto STEP = [&](float lg, float scl) {
        float e = exp2f(lg * L2E);
        if (BWD) beta = matv(Erow, beta * e * scl);
        else     beta = matv(Erow, beta * scl) * e;
    };

    float l0 = lgt(0), l1 = lgt(1), l2 = lgt(2), l3 = lgt(3);
    int k = 0;
    while (k + 4 <= nsteps) {
        float n0 = lgt(k+4), n1 = lgt(k+5), n2 = lgt(k+6), n3 = lgt(k+7);
        float scl = 1.f;
        if (k > 0) {                            // uniform; beta[0] > 0 once started
            float m = fmaxf(rdlanef(beta, 0), 1e-30f);   // NaN-proof domain guard
            M2 += log2f(m);
            scl = 1.f / m;
        }
        STEP(l0, scl); STEP(l1, 1.f); STEP(l2, 1.f); STEP(l3, 1.f);
        l0 = n0; l1 = n1; l2 = n2; l3 = n3;
        k += 4;
    }
    if (k < nsteps) {
        float scl = 1.f;
        if (k > 0) {
            float m = fmaxf(rdlanef(beta, 0), 1e-30f);
            M2 += log2f(m);
            scl = 1.f / m;
        }
        STEP(l0, scl); ++k;
        if (k < nsteps) { STEP(l1, 1.f); ++k; }
        if (k < nsteps) { STEP(l2, 1.f); ++k; }
    }
    return beta;
}

// ---- Deterministic length-rank: perm[rank] = b (ascending len, idx tiebreak)
#define LPL 16
__global__ __launch_bounds__(64) void rank_kernel(
    const int* __restrict__ lens, int* __restrict__ perm, int B)
{
    const int lane = threadIdx.x;
    int myl[LPL];
    #pragma unroll
    for (int k = 0; k < LPL; ++k) {
        int j = lane * LPL + k;
        myl[k] = (j < B) ? lens[j] : 0x7fffffff;
    }
    const int base = blockIdx.x * 64;
    for (int i = 0; i < 64; ++i) {
        int b = base + i;
        if (b >= B) break;
        int Lb = lens[b];
        int r = 0;
        #pragma unroll
        for (int k = 0; k < LPL; ++k) {
            int j = lane * LPL + k;
            r += (myl[k] < Lb || (myl[k] == Lb && j < b)) ? 1 : 0;
        }
        #pragma unroll
        for (int off = 32; off; off >>= 1) r += __shfl_xor(r, off);
        if (lane == 0) perm[r] = b;
    }
}

// One block (2 waves) per batch: wave0 fwd half, wave1 bwd half; combine after
// ONE barrier (outside all loops). Co-located blocks {m,m+256,m+512,m+768} get
// balanced ranks {m, 511-m, 512+m, 1023-m} (per-CU batch-step total constant).
// __launch_bounds__(128, 1): uncap VGPRs so Erow[52] stays out of AGPRs.
__global__ __launch_bounds__(128, 1) void crf_split_kernel(
    const float* __restrict__ logits,   // [B, T, K]
    const float* __restrict__ trans,    // [K, K]
    const int*   __restrict__ labels,   // [B, T]
    const int*   __restrict__ lens,     // [B]
    const int*   __restrict__ perm,     // [B]
    float* __restrict__ out, int B)
{
    constexpr float L2E = 1.4426950408889634f;
    constexpr float LN2 = 0.6931471805599453f;

    const int blk  = blockIdx.x;
    const int wave = threadIdx.x >> 6;
    const int lane = threadIdx.x & 63;
    const bool active = lane < KTAG;
    const bool bwd = (wave == 1);

    int r = blk;
    if (B == 4 * NCU) {
        int m = blk & (NCU - 1), j = blk >> 8;
        r = (j == 0) ? m
          : (j == 1) ? (2 * NCU - 1 - m)
          : (j == 2) ? (2 * NCU + m)
          :            (4 * NCU - 1 - m);
    }
    const int batch = perm[r];
    const int len = lens[batch];
    const int mid = len >> 1;               // fwd steps; bwd = len - mid >= 1

    // E row: wave0 = exp(trans[lane][j]) (row), wave1 = exp(trans[j][lane]) (col)
    float Erow[KTAG];
    #pragma unroll
    for (int j = 0; j < KTAG; ++j) {
        float tv = active ? (bwd ? trans[j * KTAG + lane]
                                 : trans[(size_t)lane * KTAG + j]) : 0.f;
        Erow[j] = active ? exp2f(tv * L2E) : 0.f;
    }

    const float* base = logits + (size_t)batch * TMAX * KTAG + (active ? lane : 0);

    __shared__ __align__(16) float sB[64];
    __shared__ float sM2f, sEm, sTr;

    float M2, beta;
    if (bwd) {
        float b0 = active ? exp2f(trans[STOP_TAG * KTAG + lane] * L2E) : 0.f;
        beta = chain<true>(base + (size_t)(len - 1) * KTAG, -KTAG,
                           len - 1, len - mid, Erow, b0, M2);
    } else {
        float b0 = (lane == START_TAG) ? 1.f : 0.f;
        beta = chain<false>(base, KTAG, TMAX - 1, mid, Erow, b0, M2);

        // gold-path scores on the (shorter) fwd wave; batched independent loads
        const int*   labp = labels + (size_t)batch * TMAX;
        const float* lgb  = logits + (size_t)batch * TMAX * KTAG;
        int lab[8], prv[8]; bool msk[8];
        #pragma unroll
        for (int c = 0; c < 8; ++c) {
            int tt = c * 64 + lane;
            msk[c] = tt < len;
            int ttc = msk[c] ? tt : 0;
            lab[c] = labp[ttc];
            prv[c] = (ttc == 0) ? START_TAG : labp[ttc - 1];
        }
        float em = 0.f, tr = 0.f;
        #pragma unroll
        for (int c = 0; c < 8; ++c) {
            int ttc = msk[c] ? (c * 64 + lane) : 0;
            float ev = lgb[(size_t)ttc * KTAG + lab[c]];
            float tv = trans[lab[c] * KTAG + prv[c]];
            if (msk[c]) { em += ev; tr += tv; }
        }
        if (lane == 0) tr += trans[STOP_TAG * KTAG + labp[len - 1]];
        #pragma unroll
        for (int off = 32; off; off >>= 1) {
            em += __shfl_xor(em, off);
            tr += __shfl_xor(tr, off);
        }
        sB[lane] = beta;
        if (lane == 0) { sM2f = M2; sEm = em; sTr = tr; }
    }
    __syncthreads();

    if (bwd) {
        // Z = gamma^T beta_mid
        float d = beta * sB[lane];
        #pragma unroll
        for (int off = 32; off; off >>= 1) d += __shfl_xor(d, off);
        float partition = LN2 * (sM2f + M2 + log2f(d));
        if (lane == 0) out[batch] = partition + sEm - sTr;
    }
}

extern "C" void kernel_launch(void* const* d_in, const int* in_sizes, int n_in,
                              void* d_out, int out_size, void* d_ws, size_t ws_size,
                              hipStream_t stream) {
    const float* logits = (const float*)d_in[0];
    const float* trans  = (const float*)d_in[1];
    const int*   labels = (const int*)d_in[2];
    const int*   lens   = (const int*)d_in[3];
    float* out = (float*)d_out;

    const int B = in_sizes[3];
    int* perm = (int*)d_ws;

    rank_kernel<<<dim3((B + 63) / 64), dim3(64), 0, stream>>>(lens, perm, B);
    crf_split_kernel<<<dim3(B), dim3(128), 0, stream>>>(
        logits, trans, labels, lens, perm, out, B);
}